// Round 3
// baseline (175.883 us; speedup 1.0000x reference)
//
#include <hip/hip_runtime.h>

// MixtureRouting: y[b,d,m] = sum_p x[b,d,p] * coef[b,p,m]
//   lh[b,p,m]  = pi[b,m] * prod_d( sig[b,d,m] / (PI*((mu[b,d,p]-mu[b,d,m])^2 + sig[b,d,m]^2)) )
//   coef[p,m]  = lh[p,m] / sum_m lh[p,m]
// Restructure: x'[d,p] = x[d,p] / rowsum[p];  y = x' @ lh  (lh regenerated on the fly).
// R2 -> R3: main kernel was latency-bound (VALUBusy 34%, issue-time ~= FMA floor).
// Fix: stage x' slab (128 p x 44 d) + mu chunk in LDS (24.5 KB), batch lh-computation
// x4 to pipeline the rcp chains, launch_bounds(256,4) for 4 waves/SIMD.
// x' layout changed to [b][half][p][44] so the LDS staging copy is fully contiguous.

namespace {
constexpr int BB   = 4;
constexpr int DD   = 81;
constexpr int KK   = 2048;
constexpr int PSPLIT = 16;
constexpr int PCHUNK = KK / PSPLIT;   // 128
constexpr int DSPLIT = 2;
constexpr int DHALF  = 44;            // 11 float4 per half, halves: d 0..43, 44..87 (81..87 dead)

// ws layout in floats
constexpr size_t OFF_MUP = 0;                             // float4[B*K]  packed mu
constexpr size_t OFF_S2P = (size_t)BB * KK * 4;           // float4[B*K]  packed sig^2
constexpr size_t OFF_CC  = OFF_S2P + (size_t)BB * KK * 4; // float[B*K]   c = pi*prod(sig)/PI^4
constexpr size_t OFF_IRS = OFF_CC  + (size_t)BB * KK;     // float[B*K]   1/rowsum
constexpr size_t OFF_XP  = OFF_IRS + (size_t)BB * KK;     // float[B*2*K*44] x' [b][half][p][44]
} // namespace

__global__ void pack_kernel(const float* __restrict__ pi_in,
                            const float* __restrict__ mu,
                            const float* __restrict__ sig,
                            float4* __restrict__ mu_pack,
                            float4* __restrict__ s2_pack,
                            float* __restrict__ cc) {
    int t = blockIdx.x * blockDim.x + threadIdx.x;
    if (t >= BB * KK) return;
    int b = t >> 11;
    int k = t & (KK - 1);
    const float* mub = mu  + (size_t)b * 4 * KK + k;
    const float* sgb = sig + (size_t)b * 4 * KK + k;
    float m0 = mub[0], m1 = mub[KK], m2 = mub[2 * KK], m3 = mub[3 * KK];
    float s0 = sgb[0], s1 = sgb[KK], s2 = sgb[2 * KK], s3 = sgb[3 * KK];
    mu_pack[t] = make_float4(m0, m1, m2, m3);
    s2_pack[t] = make_float4(s0 * s0, s1 * s1, s2 * s2, s3 * s3);
    const float inv_pi4 = 1.0f / 97.40909103400243f;
    cc[t] = pi_in[(size_t)b * KK + k] * ((s0 * s1) * (s2 * s3)) * inv_pi4;
}

// one block per 8 consecutive p: rowsum over m, write 1/rowsum.
__global__ __launch_bounds__(256) void rowsum_kernel(const float4* __restrict__ mu_pack,
                                                     const float4* __restrict__ s2_pack,
                                                     const float* __restrict__ cc,
                                                     float* __restrict__ invrow) {
    constexpr int PB = 8;
    int blk  = blockIdx.x;               // 0 .. B*K/PB-1
    int b    = blk >> 8;                 // 2048/8 = 256 blocks per batch
    int p0   = (blk & 255) * PB;
    int base = b << 11;

    float4 mp[PB];
#pragma unroll
    for (int i = 0; i < PB; ++i) mp[i] = mu_pack[base + p0 + i];
    float sum[PB];
#pragma unroll
    for (int i = 0; i < PB; ++i) sum[i] = 0.f;

    for (int m = threadIdx.x; m < KK; m += 256) {
        int idx = base + m;
        float4 mm = mu_pack[idx];
        float4 s2 = s2_pack[idx];
        float  c  = cc[idx];
#pragma unroll
        for (int i = 0; i < PB; ++i) {
            float d0 = mp[i].x - mm.x, d1 = mp[i].y - mm.y;
            float d2 = mp[i].z - mm.z, d3 = mp[i].w - mm.w;
            float den = fmaf(d0, d0, s2.x) * fmaf(d1, d1, s2.y) *
                        fmaf(d2, d2, s2.z) * fmaf(d3, d3, s2.w);
            sum[i] += c * __builtin_amdgcn_rcpf(den);
        }
    }

    __shared__ float red[4][PB];
    int lane = threadIdx.x & 63, w = threadIdx.x >> 6;
#pragma unroll
    for (int i = 0; i < PB; ++i) {
        float s = sum[i];
        for (int off = 32; off; off >>= 1) s += __shfl_down(s, off);
        if (lane == 0) red[w][i] = s;
    }
    __syncthreads();
    if (threadIdx.x < PB) {
        float s = red[0][threadIdx.x] + red[1][threadIdx.x] +
                  red[2][threadIdx.x] + red[3][threadIdx.x];
        invrow[base + p0 + threadIdx.x] = 1.0f / s;
    }
}

// x'[b][half][p][dl] = x[b][half*44+dl][p] / rowsum[b][p]  (dl in [0,44), dead slots zeroed)
// 64-p LDS transpose tile so global reads are coalesced over p.
__global__ __launch_bounds__(256) void xprime_kernel(const float* __restrict__ x,
                                                     const float* __restrict__ invrow,
                                                     float* __restrict__ xp) {
    constexpr int TP = 64;
    __shared__ float tile[TP][89];       // 88 d-slots, +1 pad
    int b  = blockIdx.y;
    int p0 = blockIdx.x * TP;
    int pi = threadIdx.x & 63;
    int w  = threadIdx.x >> 6;           // 4 d-lanes per p

#pragma unroll
    for (int dc = 0; dc < 21; ++dc) {
        int d = dc * 4 + w;
        if (d < DD)
            tile[pi][d] = x[(((size_t)(b * DD + d)) << 11) + p0 + pi];
    }
    __syncthreads();
    float ir = invrow[(b << 11) + p0 + pi];
    int p = p0 + pi;
#pragma unroll
    for (int j = 0; j < 22; ++j) {       // each of 4 writers covers 22 d's
        int d    = w * 22 + j;
        int half = d / 44;
        int dl   = d - half * 44;
        float v  = (d < DD) ? tile[pi][d] * ir : 0.f;
        xp[((size_t)(((b * 2 + half) << 11) + p)) * DHALF + dl] = v;
    }
}

__global__ void zero_kernel(float4* __restrict__ out, int n4) {
    int i = blockIdx.x * blockDim.x + threadIdx.x;
    if (i < n4) out[i] = make_float4(0.f, 0.f, 0.f, 0.f);
}

// grid: (K/256, PSPLIT, B*DSPLIT). Thread owns one m-column and one 44-d half.
// x' slab (128 p x 44 f32) + mu chunk staged in LDS; lh computed in batches of 4.
__global__ __launch_bounds__(256, 4) void main_kernel(const float4* __restrict__ mu_pack,
                                                      const float4* __restrict__ s2_pack,
                                                      const float* __restrict__ cc,
                                                      const float* __restrict__ xp,
                                                      float* __restrict__ out) {
    __shared__ float4 xs[PCHUNK][11];    // 22.5 KB: x' slab for this (b, half, p-chunk)
    __shared__ float4 mps[PCHUNK];       // 2 KB: mu_pack for this p-chunk

    int m     = blockIdx.x * 256 + threadIdx.x;
    int zz    = blockIdx.z;
    int b     = zz >> 1;
    int dHalf = zz & 1;
    int p0    = blockIdx.y * PCHUNK;
    int bm    = (b << 11) + m;

    // cooperative staging (fully contiguous after layout change)
    {
        const float4* src = (const float4*)xp +
                            ((size_t)(((b * 2 + dHalf) << 11) + p0)) * 11;
        float4* dst = &xs[0][0];
        for (int i = threadIdx.x; i < PCHUNK * 11; i += 256) dst[i] = src[i];
        const float4* msrc = mu_pack + (b << 11) + p0;
        for (int i = threadIdx.x; i < PCHUNK; i += 256) mps[i] = msrc[i];
    }

    float4 mm = mu_pack[bm];
    float4 s2 = s2_pack[bm];
    float  cm = cc[bm];

    float4 acc[11];
#pragma unroll
    for (int j = 0; j < 11; ++j) acc[j] = make_float4(0.f, 0.f, 0.f, 0.f);

    __syncthreads();

    for (int pb = 0; pb < PCHUNK; pb += 4) {
        float lhv[4];
#pragma unroll
        for (int q = 0; q < 4; ++q) {
            float4 mp = mps[pb + q];
            float d0 = mp.x - mm.x, d1 = mp.y - mm.y, d2 = mp.z - mm.z, d3 = mp.w - mm.w;
            float den = fmaf(d0, d0, s2.x) * fmaf(d1, d1, s2.y) *
                        fmaf(d2, d2, s2.z) * fmaf(d3, d3, s2.w);
            lhv[q] = cm * __builtin_amdgcn_rcpf(den);
        }
#pragma unroll
        for (int q = 0; q < 4; ++q) {
            float lh = lhv[q];
#pragma unroll
            for (int j = 0; j < 11; ++j) {
                float4 v = xs[pb + q][j];
                acc[j].x = fmaf(v.x, lh, acc[j].x);
                acc[j].y = fmaf(v.y, lh, acc[j].y);
                acc[j].z = fmaf(v.z, lh, acc[j].z);
                acc[j].w = fmaf(v.w, lh, acc[j].w);
            }
        }
    }

    float* ob = out + ((size_t)b * DD) * KK + m;
    const float* af = (const float*)acc;
    if (dHalf == 0) {
#pragma unroll
        for (int j = 0; j < DHALF; ++j)                 // d = 0..43, all valid
            atomicAdd(ob + (size_t)j * KK, af[j]);
    } else {
#pragma unroll
        for (int j = 0; j < DHALF; ++j) {               // d = 44..87, store d<81
            int d = DHALF + j;
            if (d < DD) atomicAdd(ob + (size_t)d * KK, af[j]);
        }
    }
}

extern "C" void kernel_launch(void* const* d_in, const int* in_sizes, int n_in,
                              void* d_out, int out_size, void* d_ws, size_t ws_size,
                              hipStream_t stream) {
    const float* x   = (const float*)d_in[0];
    const float* pi_ = (const float*)d_in[1];
    const float* mu  = (const float*)d_in[2];
    const float* sig = (const float*)d_in[3];
    float* ws  = (float*)d_ws;
    float* out = (float*)d_out;

    float4* mu_pack = (float4*)(ws + OFF_MUP);
    float4* s2_pack = (float4*)(ws + OFF_S2P);
    float*  cc      = ws + OFF_CC;
    float*  invrow  = ws + OFF_IRS;
    float*  xp      = ws + OFF_XP;

    // 1) pack per-component constants
    pack_kernel<<<(BB * KK + 255) / 256, 256, 0, stream>>>(pi_, mu, sig, mu_pack, s2_pack, cc);
    // 2) rowsums -> 1/rowsum (8 rows per block)
    rowsum_kernel<<<BB * KK / 8, 256, 0, stream>>>(mu_pack, s2_pack, cc, invrow);
    // 3) x' = x / rowsum, transposed+scaled to [b][half][p][44]
    dim3 xgrid(KK / 64, BB);
    xprime_kernel<<<xgrid, 256, 0, stream>>>(x, invrow, xp);
    // 4) zero output (harness poisons it)
    int n4 = out_size / 4;
    zero_kernel<<<(n4 + 255) / 256, 256, 0, stream>>>((float4*)out, n4);
    // 5) main contraction: LDS-staged x' slab, lh regenerated on the fly
    dim3 grid(KK / 256, PSPLIT, BB * DSPLIT);
    main_kernel<<<grid, 256, 0, stream>>>(mu_pack, s2_pack, cc, xp, out);
}

// Round 4
// 150.010 us; speedup vs baseline: 1.1725x; 1.1725x over previous
//
#include <hip/hip_runtime.h>

// MixtureRouting: y[b,d,m] = sum_p x[b,d,p] * coef[b,p,m]
//   lh[b,p,m]  = pi[b,m] * prod_d( sig[b,d,m] / (PI*((mu[b,d,p]-mu[b,d,m])^2 + sig[b,d,m]^2)) )
//   coef[p,m]  = lh[p,m] / sum_m lh[p,m]
// Restructure: x'[d,p] = x[d,p]/rowsum[p]; y = x' @ lh (lh regenerated on the fly).
// R3 -> R4:
//  (1) 5 launches -> 2: fused prep (pack-on-the-fly + rowsum + x' transpose + out-zero)
//      since total-minus-main was a constant ~75us of helper kernels/dispatch overhead.
//  (2) main: 2 m-columns per thread (88 pk-FMAs per 11 ds_read_b128) + ext-vector float4
//      math so the backend emits v_pk_fma_f32 (halves FMA issue cycles).

typedef float v4f __attribute__((ext_vector_type(4)));

namespace {
constexpr int BB = 4;
constexpr int DD = 81;
constexpr int KK = 2048;
constexpr int PSPLIT = 16;
constexpr int PCHUNK = KK / PSPLIT;   // 128
constexpr int DH = 44;                // d-half size (0..43 | 44..87, 81..87 zero-padded)
constexpr float INV_PI4 = 1.0f / 97.40909103400243f;
}

// ---------------------------------------------------------------------------
// prep: grid = BB * (KK/16) = 512 blocks, 256 threads.
// Block (b, p0=16-chunk):
//   A) rowsum[p] = sum_m lh[p,m] for its 16 p (m-side constants computed on the fly,
//      coalesced reads of raw mu/sig/pi), invrow kept in LDS only
//   B) x'[b][half][p][dl] = x[b][d][p] * invrow[p]  (d>=81 slots zeroed)
//   C) zero a 1/512 chunk of out (main accumulates with atomics)
// ---------------------------------------------------------------------------
__global__ __launch_bounds__(256) void prep_kernel(const float* __restrict__ x,
                                                   const float* __restrict__ pi_,
                                                   const float* __restrict__ mu,
                                                   const float* __restrict__ sig,
                                                   float* __restrict__ xp,
                                                   float* __restrict__ out,
                                                   int out_n4) {
    constexpr int PB = 16;
    __shared__ v4f   pmu[PB];
    __shared__ float red[4][PB];
    __shared__ float invr[PB];

    int blk = blockIdx.x;
    int b   = blk >> 7;                 // 128 p-chunks per batch
    int p0  = (blk & 127) * PB;
    int t   = threadIdx.x;

    const float* mub = mu  + (size_t)b * 4 * KK;
    const float* sgb = sig + (size_t)b * 4 * KK;
    const float* pib = pi_ + (size_t)b * KK;

    if (t < PB) {
        int p = p0 + t;
        pmu[t] = (v4f){mub[p], mub[KK + p], mub[2 * KK + p], mub[3 * KK + p]};
    }
    __syncthreads();

    float sums[PB];
#pragma unroll
    for (int i = 0; i < PB; ++i) sums[i] = 0.f;

    for (int m = t; m < KK; m += 256) {
        v4f mm = {mub[m], mub[KK + m], mub[2 * KK + m], mub[3 * KK + m]};
        v4f sg = {sgb[m], sgb[KK + m], sgb[2 * KK + m], sgb[3 * KK + m]};
        v4f s2 = sg * sg;
        float c = pib[m] * ((sg.x * sg.y) * (sg.z * sg.w)) * INV_PI4;
#pragma unroll
        for (int i = 0; i < PB; ++i) {
            v4f d = pmu[i] - mm;
            v4f q = d * d + s2;                       // v_pk_fma_f32
            float den = (q.x * q.y) * (q.z * q.w);
            sums[i] += c * __builtin_amdgcn_rcpf(den);
        }
    }

    int lane = t & 63, w = t >> 6;
#pragma unroll
    for (int i = 0; i < PB; ++i) {
        float s = sums[i];
        for (int off = 32; off; off >>= 1) s += __shfl_down(s, off);
        if (lane == 0) red[w][i] = s;
    }
    __syncthreads();
    if (t < PB)
        invr[t] = 1.0f / (red[0][t] + red[1][t] + red[2][t] + red[3][t]);
    __syncthreads();

    // B) transpose+scale x into xp[((b*2+half)*KK + p)*44 + dl]
    {
        int pl = t & 15;                // local p
        int dg = t >> 4;                // 0..15 d-lane
        int p  = p0 + pl;
        float ir = invr[pl];
#pragma unroll
        for (int k = 0; k < 6; ++k) {
            int d = dg + 16 * k;
            if (d < 2 * DH) {
                float v = (d < DD) ? x[((size_t)(b * DD + d)) * KK + p] * ir : 0.f;
                int half = (d >= DH);
                int dl   = d - half * DH;
                xp[((size_t)((b * 2 + half) * KK + p)) * DH + dl] = v;
            }
        }
    }

    // C) zero out-chunk
    {
        float4* o4 = (float4*)out;
        int per  = (out_n4 + 511) / 512;    // 324
        int base = blk * per;
        for (int i = t; i < per; i += 256) {
            int idx = base + i;
            if (idx < out_n4) o4[idx] = make_float4(0.f, 0.f, 0.f, 0.f);
        }
    }
}

// ---------------------------------------------------------------------------
// main: grid = (KK/512, PSPLIT, BB*2) = 512 blocks, 256 threads.
// Thread owns m-columns {m0, m0+256} and one 44-d half; x' slab (128p x 44d)
// + p-chunk mu staged in LDS; lh regenerated per (p, m); packed-f32 FMAs.
// ---------------------------------------------------------------------------
__global__ __launch_bounds__(256, 3) void main_kernel(const float* __restrict__ pi_,
                                                      const float* __restrict__ mu,
                                                      const float* __restrict__ sig,
                                                      const float* __restrict__ xp,
                                                      float* __restrict__ out) {
    __shared__ v4f xs[PCHUNK][11];      // 22.5 KB
    __shared__ v4f mps[PCHUNK];         // 2 KB

    int t  = threadIdx.x;
    int b  = blockIdx.z >> 1;
    int h  = blockIdx.z & 1;
    int p0 = blockIdx.y * PCHUNK;
    int m0 = blockIdx.x * 512 + t;
    int m1 = m0 + 256;

    // stage x' slab (fully contiguous) + p-side mu
    {
        const v4f* src = (const v4f*)xp + ((size_t)((b * 2 + h) * KK + p0)) * 11;
        v4f* dst = &xs[0][0];
        for (int i = t; i < PCHUNK * 11; i += 256) dst[i] = src[i];
        const float* mub = mu + (size_t)b * 4 * KK;
        if (t < PCHUNK) {
            int p = p0 + t;
            mps[t] = (v4f){mub[p], mub[KK + p], mub[2 * KK + p], mub[3 * KK + p]};
        }
    }

    // per-thread m-side constants from raw inputs (coalesced across threads)
    const float* mub = mu  + (size_t)b * 4 * KK;
    const float* sgb = sig + (size_t)b * 4 * KK;
    const float* pib = pi_ + (size_t)b * KK;
    v4f mmA = {mub[m0], mub[KK + m0], mub[2 * KK + m0], mub[3 * KK + m0]};
    v4f sgA = {sgb[m0], sgb[KK + m0], sgb[2 * KK + m0], sgb[3 * KK + m0]};
    v4f mmB = {mub[m1], mub[KK + m1], mub[2 * KK + m1], mub[3 * KK + m1]};
    v4f sgB = {sgb[m1], sgb[KK + m1], sgb[2 * KK + m1], sgb[3 * KK + m1]};
    v4f s2A = sgA * sgA;
    v4f s2B = sgB * sgB;
    float cA = pib[m0] * ((sgA.x * sgA.y) * (sgA.z * sgA.w)) * INV_PI4;
    float cB = pib[m1] * ((sgB.x * sgB.y) * (sgB.z * sgB.w)) * INV_PI4;

    v4f acc0[11], acc1[11];
#pragma unroll
    for (int j = 0; j < 11; ++j) {
        acc0[j] = (v4f)0.f;
        acc1[j] = (v4f)0.f;
    }

    __syncthreads();

    for (int p = 0; p < PCHUNK; ++p) {
        v4f mp = mps[p];                              // broadcast ds_read_b128
        v4f dA = mp - mmA;
        v4f dB = mp - mmB;
        v4f qA = dA * dA + s2A;                       // v_pk_fma_f32
        v4f qB = dB * dB + s2B;
        float lhA = cA * __builtin_amdgcn_rcpf((qA.x * qA.y) * (qA.z * qA.w));
        float lhB = cB * __builtin_amdgcn_rcpf((qB.x * qB.y) * (qB.z * qB.w));
#pragma unroll
        for (int j = 0; j < 11; ++j) {
            v4f v = xs[p][j];                         // broadcast ds_read_b128
            acc0[j] += v * lhA;                       // 2x v_pk_fma_f32
            acc1[j] += v * lhB;
        }
    }

    // epilogue: atomic accumulate (PSPLIT partial sums)
    float* ob = out + ((size_t)b * DD) * KK;
    const float* a0 = (const float*)acc0;
    const float* a1 = (const float*)acc1;
#pragma unroll
    for (int j = 0; j < DH; ++j) {
        int d = h * DH + j;
        if (d < DD) {
            atomicAdd(ob + (size_t)d * KK + m0, a0[j]);
            atomicAdd(ob + (size_t)d * KK + m1, a1[j]);
        }
    }
}

extern "C" void kernel_launch(void* const* d_in, const int* in_sizes, int n_in,
                              void* d_out, int out_size, void* d_ws, size_t ws_size,
                              hipStream_t stream) {
    const float* x   = (const float*)d_in[0];
    const float* pi_ = (const float*)d_in[1];
    const float* mu  = (const float*)d_in[2];
    const float* sig = (const float*)d_in[3];
    float* xp  = (float*)d_ws;          // B*2*K*44 floats = 2.95 MB
    float* out = (float*)d_out;

    prep_kernel<<<512, 256, 0, stream>>>(x, pi_, mu, sig, xp, out, out_size / 4);

    dim3 grid(KK / 512, PSPLIT, BB * 2);
    main_kernel<<<grid, 256, 0, stream>>>(pi_, mu, sig, xp, out);
}

// Round 5
// 120.205 us; speedup vs baseline: 1.4632x; 1.2479x over previous
//
#include <hip/hip_runtime.h>

// MixtureRouting: y[b,d,m] = sum_p x[b,d,p] * coef[b,p,m]
//   lh[b,p,m]  = pi[b,m] * prod_i( sig[b,i,m] / (PI*((mu[b,i,p]-mu[b,i,m])^2 + sig[b,i,m]^2)) )
//   coef[p,m]  = lh[p,m] / rowsum[p]
// R4 -> R5: the f32 vector path was LDS-pipe-bound (12 ds_read_b128 per p-iter per wave,
// ~3.1M b128 insts total). Threshold 0.109 vs current err 0.0078 leaves 14x headroom ->
// switch to bf16 MFMA: y = (x*invrow) @ lh with lh materialized bf16-transposed.
//   prep1: lh sweep -> lhT[b][m][p] bf16 + partial rowsums (slice-disjoint, no atomics) + zero out
//   xbf:   xbf[b][d][p] = bf16(x[b][d][p] * invrow[p]), 96 rows (81..95 zero)
//   gemm:  v_mfma_f32_16x16x32_bf16, per wave (b, 16-col tile, K-slice 256), no LDS,
//          A/B frags = 8 contiguous bf16 per lane, f32 atomicAdd epilogue.

typedef float v4f __attribute__((ext_vector_type(4)));
typedef float f32x4 __attribute__((ext_vector_type(4)));
typedef short bf16x8 __attribute__((ext_vector_type(8)));

namespace {
constexpr int BB = 4;
constexpr int DD = 81;
constexpr int KK = 2048;
constexpr int MROWS = 96;                 // padded d-rows for MFMA (6 tiles of 16)
constexpr float INV_PI4 = 1.0f / 97.40909103400243f;

// ws layout (bytes)
constexpr size_t OFF_LHT = 0;                                  // ushort[B][K][K]  33.55 MB
constexpr size_t OFF_XBF = (size_t)BB * KK * KK * 2;           // ushort[B][96][K]  1.57 MB
constexpr size_t OFF_RSP = OFF_XBF + (size_t)BB * MROWS * KK * 2; // float[B][8][K] 0.26 MB
}

__device__ __forceinline__ unsigned short f2bf(float f) {
    union { float f; unsigned int u; } v; v.f = f;
    unsigned int u = v.u;
    unsigned int r = (u + 0x7FFFu + ((u >> 16) & 1u)) >> 16;   // RNE
    return (unsigned short)r;
}

// ---------------------------------------------------------------------------
// prep1: grid = B * 32 p-chunks * 8 m-slices = 1024 blocks, 256 threads.
// Block (b, p0 = 64-chunk, ms = 256-m slice):
//   lhT[b][m][p0+lane] = bf16(lh[p,m]) for its 256 m  (contiguous 2B stores per lane)
//   rowsumPart[b][ms][p0+lane] = sum over its 256 m of lh (f32)
//   zero a 1/1024 chunk of out
// ---------------------------------------------------------------------------
__global__ __launch_bounds__(256) void prep1_kernel(const float* __restrict__ pi_,
                                                    const float* __restrict__ mu,
                                                    const float* __restrict__ sig,
                                                    unsigned short* __restrict__ lhT,
                                                    float* __restrict__ rowsumPart,
                                                    float4* __restrict__ out4,
                                                    int out_n4) {
    __shared__ v4f   mush[256];
    __shared__ v4f   s2sh[256];
    __shared__ float csh[256];
    __shared__ float red[4][64];

    int blk = blockIdx.x;
    int b   = blk >> 8;
    int pc  = (blk & 255) >> 3;          // 0..31
    int ms  = blk & 7;                   // 0..7
    int p0  = pc * 64;
    int m0  = ms * 256;
    int t   = threadIdx.x;
    int lane = t & 63, w = t >> 6;

    const float* mub = mu  + (size_t)b * 4 * KK;
    const float* sgb = sig + (size_t)b * 4 * KK;
    const float* pib = pi_ + (size_t)b * KK;

    // stage m-side constants (thread t -> m0+t)
    {
        int m = m0 + t;
        v4f mm = {mub[m], mub[KK + m], mub[2 * KK + m], mub[3 * KK + m]};
        v4f sg = {sgb[m], sgb[KK + m], sgb[2 * KK + m], sgb[3 * KK + m]};
        mush[t] = mm;
        s2sh[t] = sg * sg;
        csh[t]  = pib[m] * ((sg.x * sg.y) * (sg.z * sg.w)) * INV_PI4;
    }
    // per-lane p-side constants
    int p = p0 + lane;
    v4f mp = {mub[p], mub[KK + p], mub[2 * KK + p], mub[3 * KK + p]};
    __syncthreads();

    unsigned short* lbase = lhT + (size_t)b * KK * KK + p0 + lane;
    float sum = 0.f;
#pragma unroll 4
    for (int i = 0; i < 64; ++i) {
        int mi = w * 64 + i;                       // local m (this wave's quarter)
        v4f d = mp - mush[mi];
        v4f q = d * d + s2sh[mi];
        float den = (q.x * q.y) * (q.z * q.w);
        float lh = csh[mi] * __builtin_amdgcn_rcpf(den);
        sum += lh;
        lbase[(size_t)(m0 + mi) * KK] = f2bf(lh);
    }

    red[w][lane] = sum;
    __syncthreads();
    if (t < 64)
        rowsumPart[((size_t)(b * 8 + ms)) * KK + p0 + t] =
            red[0][t] + red[1][t] + red[2][t] + red[3][t];

    // zero out chunk (out_n4 = 165888 = 1024 * 162)
    {
        int per  = (out_n4 + 1023) / 1024;
        int base = blk * per;
        for (int i = t; i < per; i += 256) {
            int idx = base + i;
            if (idx < out_n4) out4[idx] = make_float4(0.f, 0.f, 0.f, 0.f);
        }
    }
}

// ---------------------------------------------------------------------------
// xbf: grid (96, B), 256 threads; xbf[b][d][p] = bf16(x[b][d][p] * invrow[p]); d>=81 -> 0
// ---------------------------------------------------------------------------
__global__ __launch_bounds__(256) void xbf_kernel(const float* __restrict__ x,
                                                  const float* __restrict__ rowsumPart,
                                                  unsigned short* __restrict__ xbf) {
    int d = blockIdx.x;
    int b = blockIdx.y;
    int t = threadIdx.x;
    unsigned short* orow = xbf + ((size_t)(b * MROWS + d)) * KK;
    const float* xrow = x + ((size_t)(b * DD + d)) * KK;
    const float* rsp  = rowsumPart + (size_t)b * 8 * KK;
#pragma unroll
    for (int j = 0; j < 8; ++j) {
        int p = j * 256 + t;
        float rs = 0.f;
#pragma unroll
        for (int s = 0; s < 8; ++s) rs += rsp[(size_t)s * KK + p];
        float v = 0.f;
        if (d < DD) v = xrow[p] * __builtin_amdgcn_rcpf(rs);
        orow[p] = f2bf(v);
    }
}

// ---------------------------------------------------------------------------
// gemm: 1024 blocks x 256 threads; wave = (b, nsub 16-cols, kslice of 256 p).
// Per wave: 6 M-tiles x 8 K-steps of mfma_f32_16x16x32_bf16, frags from global.
// A[m=lane&15][k=quad*8+j] from xbf rows; B[n=lane&15][k=quad*8+j] from lhT rows.
// D: col=lane&15, row=quad*4+reg. Epilogue: f32 atomicAdd (8 K-partials).
// ---------------------------------------------------------------------------
__global__ __launch_bounds__(256) void gemm_kernel(const unsigned short* __restrict__ xbf,
                                                   const unsigned short* __restrict__ lhT,
                                                   float* __restrict__ out) {
    int t = threadIdx.x;
    int w = t >> 6, lane = t & 63;
    int r = lane & 15, q = lane >> 4;

    int unit   = blockIdx.x >> 1;          // 0..511 = (b, nsub)
    int b      = unit >> 7;
    int nsub   = unit & 127;
    int kslice = ((blockIdx.x & 1) << 2) | w;
    int m0     = nsub * 16;
    int p0     = kslice * 256;

    const unsigned short* Abase = xbf + ((size_t)b * MROWS + r) * KK;
    const unsigned short* Bbase = lhT + ((size_t)(b * KK + m0 + r)) * KK;

    f32x4 acc[6];
#pragma unroll
    for (int i = 0; i < 6; ++i) acc[i] = (f32x4)0.f;

#pragma unroll
    for (int ks = 0; ks < 8; ++ks) {
        int p = p0 + ks * 32 + q * 8;
        bf16x8 Bf = *(const bf16x8*)(Bbase + p);
        bf16x8 Af[6];
#pragma unroll
        for (int Mt = 0; Mt < 6; ++Mt)
            Af[Mt] = *(const bf16x8*)(Abase + (size_t)Mt * 16 * KK + p);
#pragma unroll
        for (int Mt = 0; Mt < 6; ++Mt)
            acc[Mt] = __builtin_amdgcn_mfma_f32_16x16x32_bf16(Af[Mt], Bf, acc[Mt], 0, 0, 0);
    }

    float* ob = out + (size_t)b * DD * KK + m0 + r;
#pragma unroll
    for (int Mt = 0; Mt < 5; ++Mt) {
#pragma unroll
        for (int j = 0; j < 4; ++j) {
            int d = Mt * 16 + q * 4 + j;             // all < 80
            atomicAdd(ob + (size_t)d * KK, acc[Mt][j]);
        }
    }
    if (q == 0) atomicAdd(ob + (size_t)80 * KK, acc[5].x);   // d=80; rows 81..95 are zero
}

extern "C" void kernel_launch(void* const* d_in, const int* in_sizes, int n_in,
                              void* d_out, int out_size, void* d_ws, size_t ws_size,
                              hipStream_t stream) {
    const float* x   = (const float*)d_in[0];
    const float* pi_ = (const float*)d_in[1];
    const float* mu  = (const float*)d_in[2];
    const float* sig = (const float*)d_in[3];
    float* out = (float*)d_out;

    unsigned short* lhT = (unsigned short*)((char*)d_ws + OFF_LHT);
    unsigned short* xbf = (unsigned short*)((char*)d_ws + OFF_XBF);
    float* rowsumPart   = (float*)((char*)d_ws + OFF_RSP);

    prep1_kernel<<<1024, 256, 0, stream>>>(pi_, mu, sig, lhT, rowsumPart,
                                           (float4*)out, out_size / 4);
    dim3 xg(MROWS, BB);
    xbf_kernel<<<xg, 256, 0, stream>>>(x, rowsumPart, xbf);
    gemm_kernel<<<1024, 256, 0, stream>>>(xbf, lhT, out);
}

// Round 6
// 109.468 us; speedup vs baseline: 1.6067x; 1.0981x over previous
//
#include <hip/hip_runtime.h>

// MixtureRouting: y[b,d,m] = sum_p x[b,d,p] * coef[b,p,m]
//   lh[b,p,m]  = pi[b,m] * prod_i( sig[b,i,m] / (PI*((mu[b,i,p]-mu[b,i,m])^2 + sig[b,i,m]^2)) )
//   coef[p,m]  = lh[p,m] / rowsum[p]
// R5 -> R6: every prior main kernel floored at ~85us with WRITE_SIZE == atomic partial
// traffic (42 MB R2-R4, 21 MB R5) -> far-atomic RMW throughput was the real bottleneck.
// Fix: gemm does full-K per block (8 waves x 256-K slices), cross-wave LDS reduction,
// plain coalesced stores (2.65 MB, no atomics, no out-zeroing needed anywhere).
//   prep1: lh sweep -> lhT[b][m][p] bf16 + slice-disjoint partial rowsums
//   xbf:   xbf[b][d][p] = bf16(x[b][d][p] * invrow[p]), 96 rows (81..95 zero)
//   gemm:  v_mfma_f32_16x16x32_bf16, block = (b, 16-col m-tile), K=2048 internal.

typedef float v4f __attribute__((ext_vector_type(4)));
typedef float f32x4 __attribute__((ext_vector_type(4)));
typedef short bf16x8 __attribute__((ext_vector_type(8)));

namespace {
constexpr int BB = 4;
constexpr int DD = 81;
constexpr int KK = 2048;
constexpr int MROWS = 96;                 // padded d-rows for MFMA (6 tiles of 16)
constexpr float INV_PI4 = 1.0f / 97.40909103400243f;

// ws layout (bytes)
constexpr size_t OFF_LHT = 0;                                  // ushort[B][K][K]  33.55 MB
constexpr size_t OFF_XBF = (size_t)BB * KK * KK * 2;           // ushort[B][96][K]  1.57 MB
constexpr size_t OFF_RSP = OFF_XBF + (size_t)BB * MROWS * KK * 2; // float[B][8][K] 0.26 MB
}

__device__ __forceinline__ unsigned short f2bf(float f) {
    union { float f; unsigned int u; } v; v.f = f;
    unsigned int u = v.u;
    unsigned int r = (u + 0x7FFFu + ((u >> 16) & 1u)) >> 16;   // RNE
    return (unsigned short)r;
}

// ---------------------------------------------------------------------------
// prep1: grid = B * 32 p-chunks * 8 m-slices = 1024 blocks, 256 threads.
// Block (b, p0 = 64-chunk, ms = 256-m slice):
//   lhT[b][m][p0+lane] = bf16(lh[p,m]) for its 256 m  (contiguous 2B stores per lane)
//   rowsumPart[b][ms][p0+lane] = sum over its 256 m of lh (f32)
// ---------------------------------------------------------------------------
__global__ __launch_bounds__(256) void prep1_kernel(const float* __restrict__ pi_,
                                                    const float* __restrict__ mu,
                                                    const float* __restrict__ sig,
                                                    unsigned short* __restrict__ lhT,
                                                    float* __restrict__ rowsumPart) {
    __shared__ v4f   mush[256];
    __shared__ v4f   s2sh[256];
    __shared__ float csh[256];
    __shared__ float red[4][64];

    int blk = blockIdx.x;
    int b   = blk >> 8;
    int pc  = (blk & 255) >> 3;          // 0..31
    int ms  = blk & 7;                   // 0..7
    int p0  = pc * 64;
    int m0  = ms * 256;
    int t   = threadIdx.x;
    int lane = t & 63, w = t >> 6;

    const float* mub = mu  + (size_t)b * 4 * KK;
    const float* sgb = sig + (size_t)b * 4 * KK;
    const float* pib = pi_ + (size_t)b * KK;

    // stage m-side constants (thread t -> m0+t)
    {
        int m = m0 + t;
        v4f mm = {mub[m], mub[KK + m], mub[2 * KK + m], mub[3 * KK + m]};
        v4f sg = {sgb[m], sgb[KK + m], sgb[2 * KK + m], sgb[3 * KK + m]};
        mush[t] = mm;
        s2sh[t] = sg * sg;
        csh[t]  = pib[m] * ((sg.x * sg.y) * (sg.z * sg.w)) * INV_PI4;
    }
    // per-lane p-side constants
    int p = p0 + lane;
    v4f mp = {mub[p], mub[KK + p], mub[2 * KK + p], mub[3 * KK + p]};
    __syncthreads();

    unsigned short* lbase = lhT + (size_t)b * KK * KK + p0 + lane;
    float sum = 0.f;
#pragma unroll 4
    for (int i = 0; i < 64; ++i) {
        int mi = w * 64 + i;                       // local m (this wave's quarter)
        v4f d = mp - mush[mi];
        v4f q = d * d + s2sh[mi];
        float den = (q.x * q.y) * (q.z * q.w);
        float lh = csh[mi] * __builtin_amdgcn_rcpf(den);
        sum += lh;
        lbase[(size_t)(m0 + mi) * KK] = f2bf(lh);
    }

    red[w][lane] = sum;
    __syncthreads();
    if (t < 64)
        rowsumPart[((size_t)(b * 8 + ms)) * KK + p0 + t] =
            red[0][t] + red[1][t] + red[2][t] + red[3][t];
}

// ---------------------------------------------------------------------------
// xbf: grid (96, B), 256 threads; xbf[b][d][p] = bf16(x[b][d][p] * invrow[p]); d>=81 -> 0
// ---------------------------------------------------------------------------
__global__ __launch_bounds__(256) void xbf_kernel(const float* __restrict__ x,
                                                  const float* __restrict__ rowsumPart,
                                                  unsigned short* __restrict__ xbf) {
    int d = blockIdx.x;
    int b = blockIdx.y;
    int t = threadIdx.x;
    unsigned short* orow = xbf + ((size_t)(b * MROWS + d)) * KK;
    const float* xrow = x + ((size_t)(b * DD + d)) * KK;
    const float* rsp  = rowsumPart + (size_t)b * 8 * KK;
#pragma unroll
    for (int j = 0; j < 8; ++j) {
        int p = j * 256 + t;
        float rs = 0.f;
#pragma unroll
        for (int s = 0; s < 8; ++s) rs += rsp[(size_t)s * KK + p];
        float v = 0.f;
        if (d < DD) v = xrow[p] * __builtin_amdgcn_rcpf(rs);
        orow[p] = f2bf(v);
    }
}

// ---------------------------------------------------------------------------
// gemm: grid (128, B), 512 threads = 8 waves. Block owns (b, 16-col m-tile),
// full K=2048: wave w takes p-slice [w*256, w*256+256), 8 K-steps x 6 M-tiles of
// v_mfma_f32_16x16x32_bf16, frags straight from global.
// A[m=lane&15][k=quad*8+j] from xbf rows; B[n=lane&15][k=quad*8+j] from lhT rows.
// D: col=lane&15, row=quad*4+reg. Epilogue: 48 KB LDS cross-wave reduce + plain stores.
// ---------------------------------------------------------------------------
__global__ __launch_bounds__(512) void gemm_kernel(const unsigned short* __restrict__ xbf,
                                                   const unsigned short* __restrict__ lhT,
                                                   float* __restrict__ out) {
    __shared__ f32x4 lds[8][6][64];        // 48 KB

    int t = threadIdx.x;
    int w = t >> 6, lane = t & 63;
    int r = lane & 15, q = lane >> 4;

    int b  = blockIdx.y;
    int m0 = blockIdx.x * 16;
    int p0 = w * 256;

    const unsigned short* Abase = xbf + ((size_t)(b * MROWS + r)) * KK;
    const unsigned short* Bbase = lhT + ((size_t)(b * KK + m0 + r)) * KK;

    f32x4 acc[6];
#pragma unroll
    for (int i = 0; i < 6; ++i) acc[i] = (f32x4)0.f;

#pragma unroll 4
    for (int ks = 0; ks < 8; ++ks) {
        int p = p0 + ks * 32 + q * 8;
        bf16x8 Bf = *(const bf16x8*)(Bbase + p);
        bf16x8 Af[6];
#pragma unroll
        for (int Mt = 0; Mt < 6; ++Mt)
            Af[Mt] = *(const bf16x8*)(Abase + (size_t)Mt * 16 * KK + p);
#pragma unroll
        for (int Mt = 0; Mt < 6; ++Mt)
            acc[Mt] = __builtin_amdgcn_mfma_f32_16x16x32_bf16(Af[Mt], Bf, acc[Mt], 0, 0, 0);
    }

#pragma unroll
    for (int Mt = 0; Mt < 6; ++Mt)
        lds[w][Mt][lane] = acc[Mt];
    __syncthreads();

    // 1536 outputs (96 rows x 16 cols), 512 threads -> 3 each; skip d >= 81.
    int col = t & 15;
    int dr  = t >> 4;                      // 0..31
#pragma unroll
    for (int k = 0; k < 3; ++k) {
        int d = dr + 32 * k;               // 0..95
        if (d < DD) {
            int Mt  = d >> 4;
            int row = d & 15;
            int l   = (row >> 2) * 16 + col;
            int j   = row & 3;
            float s = 0.f;
#pragma unroll
            for (int ww = 0; ww < 8; ++ww) s += lds[ww][Mt][l][j];
            out[((size_t)(b * DD + d)) * KK + m0 + col] = s;
        }
    }
}

extern "C" void kernel_launch(void* const* d_in, const int* in_sizes, int n_in,
                              void* d_out, int out_size, void* d_ws, size_t ws_size,
                              hipStream_t stream) {
    const float* x   = (const float*)d_in[0];
    const float* pi_ = (const float*)d_in[1];
    const float* mu  = (const float*)d_in[2];
    const float* sig = (const float*)d_in[3];
    float* out = (float*)d_out;

    unsigned short* lhT = (unsigned short*)((char*)d_ws + OFF_LHT);
    unsigned short* xbf = (unsigned short*)((char*)d_ws + OFF_XBF);
    float* rowsumPart   = (float*)((char*)d_ws + OFF_RSP);

    prep1_kernel<<<1024, 256, 0, stream>>>(pi_, mu, sig, lhT, rowsumPart);
    dim3 xg(MROWS, BB);
    xbf_kernel<<<xg, 256, 0, stream>>>(x, rowsumPart, xbf);
    dim3 gg(KK / 16, BB);
    gemm_kernel<<<gg, 512, 0, stream>>>(xbf, lhT, out);
}

// Round 7
// 100.161 us; speedup vs baseline: 1.7560x; 1.0929x over previous
//
#include <hip/hip_runtime.h>

// MixtureRouting: y[b,d,m] = sum_p x[b,d,p] * coef[b,p,m]
//   lh[b,p,m]  = pi[b,m] * prod_i( sig[b,i,m] / (PI*((mu[b,i,p]-mu[b,i,m])^2 + sig[b,i,m]^2)) )
//   coef[p,m]  = lh[p,m] / rowsum[p]
// R6 -> R7: our kernels summed to ~60us vs ~15us model; the suspect is the lhT round
// trip (33.5 MB HBM write in prep1 + 33.5 MB latency-serialized scattered B-frag reads
// in gemm). Fix: fuse lh generation into the GEMM -- each lane computes its own 8-value
// B-fragment in registers from LDS-staged mu[b] + per-lane m-constants. lhT is never
// materialized. prep1 degenerates to a pure rowsum pass; xbf unchanged (folds invrow
// into the bf16 A matrix). gemm LDS: 32 KB mu buffer, reused post-barrier as the 48 KB
// cross-wave reduction buffer (union).

typedef float v4f __attribute__((ext_vector_type(4)));
typedef float f32x4 __attribute__((ext_vector_type(4)));
typedef short bf16x8 __attribute__((ext_vector_type(8)));

namespace {
constexpr int BB = 4;
constexpr int DD = 81;
constexpr int KK = 2048;
constexpr int MROWS = 96;                 // padded d-rows for MFMA (6 tiles of 16)
constexpr float INV_PI4 = 1.0f / 97.40909103400243f;

// ws layout (bytes) -- only 1.8 MB used now
constexpr size_t OFF_XBF = 0;                                     // ushort[B][96][K]
constexpr size_t OFF_RSP = (size_t)BB * MROWS * KK * 2;           // float[B][8][K]
}

__device__ __forceinline__ unsigned short f2bf(float f) {
    union { float f; unsigned int u; } v; v.f = f;
    unsigned int u = v.u;
    unsigned int r = (u + 0x7FFFu + ((u >> 16) & 1u)) >> 16;   // RNE
    return (unsigned short)r;
}

// ---------------------------------------------------------------------------
// rowsum: grid = B * 32 p-chunks * 8 m-slices = 1024 blocks, 256 threads.
// Block (b, p0 = 64-chunk, ms = 256-m slice):
//   rowsumPart[b][ms][p0+lane] = sum over its 256 m of lh[p,m]  (f32, slice-disjoint)
// ---------------------------------------------------------------------------
__global__ __launch_bounds__(256) void rowsum_kernel(const float* __restrict__ pi_,
                                                     const float* __restrict__ mu,
                                                     const float* __restrict__ sig,
                                                     float* __restrict__ rowsumPart) {
    __shared__ v4f   mush[256];
    __shared__ v4f   s2sh[256];
    __shared__ float csh[256];
    __shared__ float red[4][64];

    int blk = blockIdx.x;
    int b   = blk >> 8;
    int pc  = (blk & 255) >> 3;          // 0..31
    int ms  = blk & 7;                   // 0..7
    int p0  = pc * 64;
    int m0  = ms * 256;
    int t   = threadIdx.x;
    int lane = t & 63, w = t >> 6;

    const float* mub = mu  + (size_t)b * 4 * KK;
    const float* sgb = sig + (size_t)b * 4 * KK;
    const float* pib = pi_ + (size_t)b * KK;

    // stage m-side constants (thread t -> m0+t)
    {
        int m = m0 + t;
        v4f mm = {mub[m], mub[KK + m], mub[2 * KK + m], mub[3 * KK + m]};
        v4f sg = {sgb[m], sgb[KK + m], sgb[2 * KK + m], sgb[3 * KK + m]};
        mush[t] = mm;
        s2sh[t] = sg * sg;
        csh[t]  = pib[m] * ((sg.x * sg.y) * (sg.z * sg.w)) * INV_PI4;
    }
    // per-lane p-side constants
    int p = p0 + lane;
    v4f mp = {mub[p], mub[KK + p], mub[2 * KK + p], mub[3 * KK + p]};
    __syncthreads();

    float sum = 0.f;
#pragma unroll 4
    for (int i = 0; i < 64; ++i) {
        int mi = w * 64 + i;                       // local m (this wave's quarter)
        v4f d = mp - mush[mi];
        v4f q = d * d + s2sh[mi];
        float den = (q.x * q.y) * (q.z * q.w);
        sum += csh[mi] * __builtin_amdgcn_rcpf(den);
    }

    red[w][lane] = sum;
    __syncthreads();
    if (t < 64)
        rowsumPart[((size_t)(b * 8 + ms)) * KK + p0 + t] =
            red[0][t] + red[1][t] + red[2][t] + red[3][t];
}

// ---------------------------------------------------------------------------
// xbf: grid (96, B), 256 threads; xbf[b][d][p] = bf16(x[b][d][p] * invrow[p]); d>=81 -> 0
// ---------------------------------------------------------------------------
__global__ __launch_bounds__(256) void xbf_kernel(const float* __restrict__ x,
                                                  const float* __restrict__ rowsumPart,
                                                  unsigned short* __restrict__ xbf) {
    int d = blockIdx.x;
    int b = blockIdx.y;
    int t = threadIdx.x;
    unsigned short* orow = xbf + ((size_t)(b * MROWS + d)) * KK;
    const float* xrow = x + ((size_t)(b * DD + d)) * KK;
    const float* rsp  = rowsumPart + (size_t)b * 8 * KK;
#pragma unroll
    for (int j = 0; j < 8; ++j) {
        int p = j * 256 + t;
        float rs = 0.f;
#pragma unroll
        for (int s = 0; s < 8; ++s) rs += rsp[(size_t)s * KK + p];
        float v = 0.f;
        if (d < DD) v = xrow[p] * __builtin_amdgcn_rcpf(rs);
        orow[p] = f2bf(v);
    }
}

// ---------------------------------------------------------------------------
// gemm (fused lh): grid (128, B), 512 threads = 8 waves. Block = (b, 16-col m-tile),
// full K=2048; wave w owns p-slice [w*256, w*256+256).
// Per ks-step: lane (r,q) COMPUTES its B-fragment lh[p=pb..pb+7][m=m0+r] in registers
// (mu[b] staged as float4[2048] in LDS; m-side constants per-lane), loads 6 A-frags
// from xbf (L2-resident), 6x v_mfma_f32_16x16x32_bf16.
// A[m=lane&15][k=quad*8+j]; B[n=lane&15][k=quad*8+j]; D col=lane&15,row=quad*4+reg.
// Epilogue: cross-wave LDS reduce (reuses mu buffer) + plain coalesced stores.
// ---------------------------------------------------------------------------
__global__ __launch_bounds__(512) void gemm_kernel(const float* __restrict__ pi_,
                                                   const float* __restrict__ mu,
                                                   const float* __restrict__ sig,
                                                   const unsigned short* __restrict__ xbf,
                                                   float* __restrict__ out) {
    __shared__ __align__(16) char smem[49152];          // 48 KB
    v4f* mus = (v4f*)smem;                              // [2048] during K-loop (32 KB)
    f32x4 (*red)[6][64] = (f32x4 (*)[6][64])smem;       // [8][6][64] after barrier (48 KB)

    int t = threadIdx.x;
    int w = t >> 6, lane = t & 63;
    int r = lane & 15, q = lane >> 4;
    int b  = blockIdx.y;
    int m0 = blockIdx.x * 16;

    const float* mub = mu  + (size_t)b * 4 * KK;
    const float* sgb = sig + (size_t)b * 4 * KK;

    // stage mu[b] transposed: mus[p] = {mu0[p], mu1[p], mu2[p], mu3[p]}
    for (int i = t; i < KK; i += 512)
        mus[i] = (v4f){mub[i], mub[KK + i], mub[2 * KK + i], mub[3 * KK + i]};

    // per-lane m-side constants (m = m0 + r)
    int m = m0 + r;
    v4f mm = {mub[m], mub[KK + m], mub[2 * KK + m], mub[3 * KK + m]};
    v4f sg = {sgb[m], sgb[KK + m], sgb[2 * KK + m], sgb[3 * KK + m]};
    v4f s2 = sg * sg;
    float cm = pi_[(size_t)b * KK + m] * ((sg.x * sg.y) * (sg.z * sg.w)) * INV_PI4;

    const unsigned short* Abase = xbf + ((size_t)(b * MROWS + r)) * KK;

    f32x4 acc[6];
#pragma unroll
    for (int i = 0; i < 6; ++i) acc[i] = (f32x4)0.f;

    __syncthreads();

    int pw = w * 256;
#pragma unroll
    for (int ks = 0; ks < 8; ++ks) {
        int pb = pw + ks * 32 + q * 8;
        // build B fragment in registers: Bf[j] = bf16(lh[pb+j][m0+r])
        bf16x8 Bf;
#pragma unroll
        for (int j = 0; j < 8; ++j) {
            v4f mp = mus[pb + j];
            v4f dd = mp - mm;
            v4f qq = dd * dd + s2;
            float den = (qq.x * qq.y) * (qq.z * qq.w);
            float lh = cm * __builtin_amdgcn_rcpf(den);
            Bf[j] = (short)f2bf(lh);
        }
        bf16x8 Af[6];
#pragma unroll
        for (int Mt = 0; Mt < 6; ++Mt)
            Af[Mt] = *(const bf16x8*)(Abase + (size_t)Mt * 16 * KK + pb);
#pragma unroll
        for (int Mt = 0; Mt < 6; ++Mt)
            acc[Mt] = __builtin_amdgcn_mfma_f32_16x16x32_bf16(Af[Mt], Bf, acc[Mt], 0, 0, 0);
    }

    __syncthreads();                     // all waves done reading mus -> safe to reuse
#pragma unroll
    for (int Mt = 0; Mt < 6; ++Mt)
        red[w][Mt][lane] = acc[Mt];
    __syncthreads();

    // 1536 outputs (96 rows x 16 cols), 512 threads -> 3 each; skip d >= 81.
    int col = t & 15;
    int dr  = t >> 4;                    // 0..31
#pragma unroll
    for (int k = 0; k < 3; ++k) {
        int d = dr + 32 * k;             // 0..95
        if (d < DD) {
            int Mt  = d >> 4;
            int row = d & 15;
            int l   = (row >> 2) * 16 + col;
            int j   = row & 3;
            float s = 0.f;
#pragma unroll
            for (int ww = 0; ww < 8; ++ww) s += red[ww][Mt][l][j];
            out[((size_t)(b * DD + d)) * KK + m0 + col] = s;
        }
    }
}

extern "C" void kernel_launch(void* const* d_in, const int* in_sizes, int n_in,
                              void* d_out, int out_size, void* d_ws, size_t ws_size,
                              hipStream_t stream) {
    const float* x   = (const float*)d_in[0];
    const float* pi_ = (const float*)d_in[1];
    const float* mu  = (const float*)d_in[2];
    const float* sig = (const float*)d_in[3];
    float* out = (float*)d_out;

    unsigned short* xbf = (unsigned short*)((char*)d_ws + OFF_XBF);
    float* rowsumPart   = (float*)((char*)d_ws + OFF_RSP);

    rowsum_kernel<<<1024, 256, 0, stream>>>(pi_, mu, sig, rowsumPart);
    dim3 xg(MROWS, BB);
    xbf_kernel<<<xg, 256, 0, stream>>>(x, rowsumPart, xbf);
    dim3 gg(KK / 16, BB);
    gemm_kernel<<<gg, 512, 0, stream>>>(pi_, mu, sig, xbf, out);
}